// Round 11
// baseline (913.109 us; speedup 1.0000x reference)
//
#include <hip/hip_runtime.h>
#include <cstdint>

typedef unsigned short u16;
typedef unsigned int   u32;
typedef u16   u16x8 __attribute__((ext_vector_type(8)));
typedef u16   u16x4 __attribute__((ext_vector_type(4)));
typedef float f32x4 __attribute__((ext_vector_type(4)));
typedef __bf16 bf16x8 __attribute__((ext_vector_type(8)));

#define NB    256      // windows (16x16 grid)
#define WTOK  49       // tokens per window (7x7)
#define CH    512
#define HEADS 8
#define DH    64
#define TOK   100352   // 8*256*49

// ---------- helpers ----------
__device__ __forceinline__ u16 f2bf(float f) {
  u32 u = __float_as_uint(f);
  u = (u + 0x7FFFu + ((u >> 16) & 1u)) >> 16;
  return (u16)u;
}
__device__ __forceinline__ float bf2f(u16 u) { return __uint_as_float(((u32)u) << 16); }

__device__ __forceinline__ void load_lds16(const void* g, void* l) {
  __builtin_amdgcn_global_load_lds(
      reinterpret_cast<__attribute__((address_space(1))) void*>(reinterpret_cast<uintptr_t>(g)),
      reinterpret_cast<__attribute__((address_space(3))) void*>(reinterpret_cast<uintptr_t>(l)),
      16, 0, 0);
}

// ---------- small prep kernels ----------
__global__ void cvt_f32_bf16(const float* __restrict__ in, u16* __restrict__ out, int n8) {
  int i = blockIdx.x * 256 + threadIdx.x;
  if (i < n8) {
    f32x4 a = *(const f32x4*)(in + (long)i * 8);
    f32x4 b = *(const f32x4*)(in + (long)i * 8 + 4);
    u16x8 o;
    o[0]=f2bf(a[0]); o[1]=f2bf(a[1]); o[2]=f2bf(a[2]); o[3]=f2bf(a[3]);
    o[4]=f2bf(b[0]); o[5]=f2bf(b[1]); o[6]=f2bf(b[2]); o[7]=f2bf(b[3]);
    *(u16x8*)(out + (long)i * 8) = o;
  }
}

__global__ void prep_wle(const float* __restrict__ lepe_w, float* __restrict__ wle) {
  int i = blockIdx.x * 256 + threadIdx.x;   // 12800 = 512*25
  if (i < 12800) {
    int c = i / 25, kk = i % 25;
    wle[kk * 512 + c] = lepe_w[i];
  }
}

// block-weight matrix: mat[i,j] = cos(d(i,j)/dmax * pi/4), column-normalized over i
__global__ void weight_kernel(u16* __restrict__ Wbf, float* __restrict__ Wt) {
  int j = blockIdx.x, i = threadIdx.x;
  float iy = (float)(i >> 4) + 0.5f, ix = (float)(i & 15) + 0.5f;
  float jy = (float)(j >> 4) + 0.5f, jx = (float)(j & 15) + 0.5f;
  float dy = iy - jy, dx = ix - jx;
  float d = sqrtf(dy * dy + dx * dx);
  const float dmax = 21.213203435596427f;           // sqrt(450)
  float m = cosf(d * (0.78539816339744831f / dmax)); // pi/4 / dmax
  __shared__ float red[256];
  red[i] = m;
  __syncthreads();
  for (int s = 128; s > 0; s >>= 1) {
    if (i < s) red[i] += red[i + s];
    __syncthreads();
  }
  float w = m / red[0];
  Wbf[i * 256 + j] = f2bf(w);
  Wt[j * 256 + i] = w;
}

// ---------- LayerNorm (wave per token) ----------
__global__ __launch_bounds__(256) void ln_kernel(const float* __restrict__ x,
                                                 const float* __restrict__ g,
                                                 const float* __restrict__ bta,
                                                 u16* __restrict__ xn) {
  int wave = threadIdx.x >> 6, lane = threadIdx.x & 63;
  long t = (long)blockIdx.x * 4 + wave;
  const float* xp = x + t * CH + lane * 8;
  f32x4 a = *(const f32x4*)xp;
  f32x4 b = *(const f32x4*)(xp + 4);
  float s  = a[0]+a[1]+a[2]+a[3]+b[0]+b[1]+b[2]+b[3];
  float sq = a[0]*a[0]+a[1]*a[1]+a[2]*a[2]+a[3]*a[3]+b[0]*b[0]+b[1]*b[1]+b[2]*b[2]+b[3]*b[3];
  for (int m = 1; m < 64; m <<= 1) { s += __shfl_xor(s, m); sq += __shfl_xor(sq, m); }
  float mu = s * (1.0f / 512.0f);
  float var = sq * (1.0f / 512.0f) - mu * mu;
  float rstd = rsqrtf(var + 1e-5f);
  const float* gp = g + lane * 8;
  const float* bp = bta + lane * 8;
  f32x4 g0 = *(const f32x4*)gp, g1 = *(const f32x4*)(gp + 4);
  f32x4 b0 = *(const f32x4*)bp, b1 = *(const f32x4*)(bp + 4);
  u16x8 o;
  o[0] = f2bf((a[0]-mu)*rstd*g0[0] + b0[0]);
  o[1] = f2bf((a[1]-mu)*rstd*g0[1] + b0[1]);
  o[2] = f2bf((a[2]-mu)*rstd*g0[2] + b0[2]);
  o[3] = f2bf((a[3]-mu)*rstd*g0[3] + b0[3]);
  o[4] = f2bf((b[0]-mu)*rstd*g1[0] + b1[0]);
  o[5] = f2bf((b[1]-mu)*rstd*g1[1] + b1[1]);
  o[6] = f2bf((b[2]-mu)*rstd*g1[2] + b1[2]);
  o[7] = f2bf((b[3]-mu)*rstd*g1[3] + b1[3]);
  *(u16x8*)(xn + t * CH + lane * 8) = o;
}

// ============ 8-phase 256x256 GEMM (m201 template), K=512 ============
// BK=64, 2 LDS buffers x (A 32KB + B 32KB), each operand split in 2 K-halves
// of 16KB.  Per K-tile: 4 phases {ds_reads ; stage 1 half-tile ; barrier ;
// lgkmcnt(0)+sched_barrier ; 16 MFMA ; [vmcnt(4) at P1/P3] ; barrier}.
// st_16x32 swizzle: lds byte = row*64 + (kb ^ ((row>>3&1)<<5)); applied as
// inverse-swizzled global SOURCE + swizzled READ (linear global_load_lds dest).
#define MFMA_BF16 __builtin_amdgcn_mfma_f32_16x16x32_bf16

template <int KT>
__device__ __forceinline__ void ktileT(char* sm, const u16* sAst, const u16* sBst,
                                       int t, int aoff, int boff,
                                       f32x4 (&acc)[8][4]) {
  const char* rb = sm + (KT & 1) * 65536;
  char* wb = sm + ((KT + 1) & 1) * 65536;
  bf16x8 fa[4], fb[4];
  // ---- phase 0: ks0, m0-3 (12 ds_reads) ; stage A-ks0 of KT+1 ----
#pragma unroll
  for (int m = 0; m < 4; m++) fa[m] = *(const bf16x8*)(rb + aoff + m * 1024);
#pragma unroll
  for (int n = 0; n < 4; n++) fb[n] = *(const bf16x8*)(rb + boff + n * 1024);
  if constexpr (KT + 1 < 8) {
    const u16* s = sAst + (KT + 1) * 64;
    char* d = wb + t * 16;
    load_lds16(s, d);
    load_lds16(s + 65536, d + 8192);
  }
  __builtin_amdgcn_s_barrier();
  asm volatile("s_waitcnt lgkmcnt(0)" ::: "memory");
  __builtin_amdgcn_sched_barrier(0);
  __builtin_amdgcn_s_setprio(1);
#pragma unroll
  for (int m = 0; m < 4; m++)
#pragma unroll
    for (int n = 0; n < 4; n++)
      acc[m][n] = MFMA_BF16(fa[m], fb[n], acc[m][n], 0, 0, 0);
  __builtin_amdgcn_s_setprio(0);
  __builtin_amdgcn_s_barrier();
  // ---- phase 1: ks0, m4-7 (4 ds_reads) ; stage B-ks0 of KT+1 ; vmcnt ----
#pragma unroll
  for (int m = 0; m < 4; m++) fa[m] = *(const bf16x8*)(rb + aoff + (4 + m) * 1024);
  if constexpr (KT + 1 < 8) {
    const u16* s = sBst + (KT + 1) * 64;
    char* d = wb + 32768 + t * 16;
    load_lds16(s, d);
    load_lds16(s + 65536, d + 8192);
  }
  __builtin_amdgcn_s_barrier();
  asm volatile("s_waitcnt lgkmcnt(0)" ::: "memory");
  __builtin_amdgcn_sched_barrier(0);
  __builtin_amdgcn_s_setprio(1);
#pragma unroll
  for (int m = 0; m < 4; m++)
#pragma unroll
    for (int n = 0; n < 4; n++)
      acc[4 + m][n] = MFMA_BF16(fa[m], fb[n], acc[4 + m][n], 0, 0, 0);
  __builtin_amdgcn_s_setprio(0);
  if constexpr (KT < 7) {
    asm volatile("s_waitcnt vmcnt(4)" ::: "memory");   // this tile's ks1 landed
  } else {
    asm volatile("s_waitcnt vmcnt(0)" ::: "memory");
  }
  __builtin_amdgcn_s_barrier();
  // ---- phase 2: ks1, m0-3 (12 ds_reads) ; stage A-ks1 of KT+1 ----
#pragma unroll
  for (int m = 0; m < 4; m++) fa[m] = *(const bf16x8*)(rb + 16384 + aoff + m * 1024);
#pragma unroll
  for (int n = 0; n < 4; n++) fb[n] = *(const bf16x8*)(rb + 16384 + boff + n * 1024);
  if constexpr (KT + 1 < 8) {
    const u16* s = sAst + (KT + 1) * 64 + 32;
    char* d = wb + 16384 + t * 16;
    load_lds16(s, d);
    load_lds16(s + 65536, d + 8192);
  }
  __builtin_amdgcn_s_barrier();
  asm volatile("s_waitcnt lgkmcnt(0)" ::: "memory");
  __builtin_amdgcn_sched_barrier(0);
  __builtin_amdgcn_s_setprio(1);
#pragma unroll
  for (int m = 0; m < 4; m++)
#pragma unroll
    for (int n = 0; n < 4; n++)
      acc[m][n] = MFMA_BF16(fa[m], fb[n], acc[m][n], 0, 0, 0);
  __builtin_amdgcn_s_setprio(0);
  __builtin_amdgcn_s_barrier();
  // ---- phase 3: ks1, m4-7 (4 ds_reads) ; stage B-ks1 of KT+1 ; vmcnt ----
#pragma unroll
  for (int m = 0; m < 4; m++) fa[m] = *(const bf16x8*)(rb + 16384 + aoff + (4 + m) * 1024);
  if constexpr (KT + 1 < 8) {
    const u16* s = sBst + (KT + 1) * 64 + 32;
    char* d = wb + 49152 + t * 16;
    load_lds16(s, d);
    load_lds16(s + 65536, d + 8192);
  }
  __builtin_amdgcn_s_barrier();
  asm volatile("s_waitcnt lgkmcnt(0)" ::: "memory");
  __builtin_amdgcn_sched_barrier(0);
  __builtin_amdgcn_s_setprio(1);
#pragma unroll
  for (int m = 0; m < 4; m++)
#pragma unroll
    for (int n = 0; n < 4; n++)
      acc[4 + m][n] = MFMA_BF16(fa[m], fb[n], acc[4 + m][n], 0, 0, 0);
  __builtin_amdgcn_s_setprio(0);
  if constexpr (KT < 7) {
    asm volatile("s_waitcnt vmcnt(4)" ::: "memory");   // next tile's ks0 landed
  }
  __builtin_amdgcn_s_barrier();
}

// EPI: 1 = bf16, relu+eps cols<1024 -> qk; cols>=1024 -> vimg (fold_v fused)
// EPI: 2 = f32 out + bias
template <int EPI>
__global__ __launch_bounds__(512, 2)
void gemmT(const u16* __restrict__ A, const u16* __restrict__ B,
           void* __restrict__ C, u16* __restrict__ vimg,
           const float* __restrict__ bias, int ldc, int nbn) {
  __shared__ __align__(16) char sm[131072];
  const int nwg = gridDim.x, bid = blockIdx.x;
  const int cpx = nwg >> 3;
  const int vid = (bid & 7) * cpx + (bid >> 3);   // XCD-contiguous chunks
  const int bn = vid % nbn, bm = vid / nbn;
  const int t = threadIdx.x, lane = t & 63, wave = t >> 6;
  const int wm = wave >> 2, wn = wave & 3;        // 2M x 4N
  const int fr = lane & 15, fq = lane >> 4;
  // staging source (inverse st_16x32 swizzle)
  const int kcolsw = ((t & 3) * 8) ^ (((t >> 5) & 1) * 16);
  const u16* sAst = A + ((long)bm * 256 + (t >> 2)) * 512 + kcolsw;
  const u16* sBst = B + ((long)bn * 256 + (t >> 2)) * 512 + kcolsw;
  // fragment read offsets (swizzled)
  const int fsw = (fq * 16) ^ ((fr >> 3) << 5);
  const int aoff = (wm * 128 + fr) * 64 + fsw;            // + mf*1024, + h*16384
  const int boff = 32768 + (wn * 64 + fr) * 64 + fsw;     // + nf*1024, + h*16384
  f32x4 acc[8][4] = {};
  // prologue: stage tile 0 (ks0 first, then ks1)
  {
    char* d0 = sm + t * 16;
    load_lds16(sAst, d0);
    load_lds16(sAst + 65536, d0 + 8192);
    load_lds16(sBst, d0 + 32768);
    load_lds16(sBst + 65536, d0 + 40960);
    __builtin_amdgcn_sched_barrier(0);
    load_lds16(sAst + 32, d0 + 16384);
    load_lds16(sAst + 65536 + 32, d0 + 24576);
    load_lds16(sBst + 32, d0 + 49152);
    load_lds16(sBst + 65536 + 32, d0 + 57344);
  }
  asm volatile("s_waitcnt vmcnt(4)" ::: "memory");        // ks0 halves landed
  __builtin_amdgcn_s_barrier();
  ktileT<0>(sm, sAst, sBst, t, aoff, boff, acc);
  ktileT<1>(sm, sAst, sBst, t, aoff, boff, acc);
  ktileT<2>(sm, sAst, sBst, t, aoff, boff, acc);
  ktileT<3>(sm, sAst, sBst, t, aoff, boff, acc);
  ktileT<4>(sm, sAst, sBst, t, aoff, boff, acc);
  ktileT<5>(sm, sAst, sBst, t, aoff, boff, acc);
  ktileT<6>(sm, sAst, sBst, t, aoff, boff, acc);
  ktileT<7>(sm, sAst, sBst, t, aoff, boff, acc);
  // ---- epilogue: per-wave LDS repack -> vectorized stores ----
  {
    float* ep = (float*)sm + wave * 1088;      // [16 rows][68 f32] per wave
    const long r0 = (long)bm * 256 + wm * 128;
    const int c0 = bn * 256 + wn * 64;
    const int rrow = lane >> 2;
    const int cb = (lane & 3) * 16;
    const int cc = c0 + cb;
#pragma unroll
    for (int m = 0; m < 8; m++) {
#pragma unroll
      for (int n = 0; n < 4; n++) {
        int c = c0 + n * 16 + fr;
        float badd = (EPI == 2) ? bias[c] : 0.0f;
#pragma unroll
        for (int jj = 0; jj < 4; jj++) {
          float v = acc[m][n][jj];
          if (EPI == 1) { if (c < 1024) v = fmaxf(v, 0.0f) + 1e-6f; }
          if (EPI == 2) v += badd;
          ep[(fq * 4 + jj) * 68 + n * 16 + fr] = v;
        }
      }
      f32x4 rr[4];
#pragma unroll
      for (int i = 0; i < 4; i++)
        rr[i] = *(const f32x4*)&ep[rrow * 68 + cb + i * 4];
      long gr = r0 + m * 16 + rrow;
      if (EPI == 2) {
        float* gp = (float*)C + gr * ldc + cc;
#pragma unroll
        for (int i = 0; i < 4; i++) *(f32x4*)(gp + i * 4) = rr[i];
      } else {
        u16x8 o0, o1;
#pragma unroll
        for (int i = 0; i < 4; i++) {
          o0[i] = f2bf(rr[0][i]); o0[4 + i] = f2bf(rr[1][i]);
          o1[i] = f2bf(rr[2][i]); o1[4 + i] = f2bf(rr[3][i]);
        }
        u16* gp;
        if (cc < 1024) {
          gp = (u16*)C + gr * ldc + cc;
        } else {
          // fused fold_v: token -> padded image position
          int tok = (int)gr;
          int b2 = tok / 12544;
          int rem = tok - b2 * 12544;
          int nn = rem / 49;
          int w = rem - nn * 49;
          int wi = w / 7, wj = w - wi * 7;
          int y = (nn >> 4) * 7 + wi + 2;
          int xx = (nn & 15) * 7 + wj + 2;
          gp = vimg + (((long)(b2 * 116 + y)) * 116 + xx) * 512 + (cc - 1024);
        }
        *(u16x8*)gp = o0;
        *(u16x8*)(gp + 8) = o1;
      }
    }
  }
}

// ---------- m97-style B^T GEMM (mix GEMM) ----------
template <int EPI>
__global__ __launch_bounds__(256)
void gemm_bt(const u16* __restrict__ A, const u16* __restrict__ B,
             void* __restrict__ C, const float* __restrict__ bias,
             int M, int N, int K, long sAb, long sBb, long sCb) {
  __shared__ u16 As[128 * 32];
  __shared__ u16 Bs[128 * 32];
  const int tid = threadIdx.x;
  const int lane = tid & 63;
  const int wave = tid >> 6;
  const int fr = lane & 15, fq = lane >> 4;
  const int wr = (wave >> 1) * 64, wc = (wave & 1) * 64;
  const long bm = blockIdx.y, bn = blockIdx.x, bz = blockIdx.z;
  const u16* Ab = A + bz * sAb + bm * 128 * (long)K;
  const u16* Bb = B + bz * sBb + bn * 128 * (long)K;
  const int srow = tid >> 2;
  const int scol = (tid & 3) * 8;
  f32x4 acc[4][4] = {};
  for (int k0 = 0; k0 < K; k0 += 32) {
    load_lds16(Ab + (long)srow * K + k0 + scol, As + tid * 8);
    load_lds16(Ab + (long)(srow + 64) * K + k0 + scol, As + 2048 + tid * 8);
    load_lds16(Bb + (long)srow * K + k0 + scol, Bs + tid * 8);
    load_lds16(Bb + (long)(srow + 64) * K + k0 + scol, Bs + 2048 + tid * 8);
    __syncthreads();
    bf16x8 af[4], bf[4];
#pragma unroll
    for (int m = 0; m < 4; m++) af[m] = *(const bf16x8*)&As[(wr + m * 16 + fr) * 32 + fq * 8];
#pragma unroll
    for (int n = 0; n < 4; n++) bf[n] = *(const bf16x8*)&Bs[(wc + n * 16 + fr) * 32 + fq * 8];
#pragma unroll
    for (int m = 0; m < 4; m++)
#pragma unroll
      for (int n = 0; n < 4; n++)
        acc[m][n] = MFMA_BF16(af[m], bf[n], acc[m][n], 0, 0, 0);
    __syncthreads();
  }
#pragma unroll
  for (int m = 0; m < 4; m++) {
    int r0 = wr + m * 16 + fq * 4;
#pragma unroll
    for (int n = 0; n < 4; n++) {
      int c = (int)bn * 128 + wc + n * 16 + fr;
#pragma unroll
      for (int jj = 0; jj < 4; jj++) {
        long r = bm * 128 + r0 + jj;
        float v = acc[m][n][jj];
        if (EPI == 1) { if (c < 1024) v = fmaxf(v, 0.0f) + 1e-6f; }
        if (EPI == 2) {
          ((float*)C)[bz * sCb + r * N + c] = v + bias[c];
        } else {
          ((u16*)C)[bz * sCb + r * N + c] = f2bf(v);
        }
      }
    }
  }
}

// zero the 2-wide border of vimg
__global__ __launch_bounds__(256)
void zero_border(u16* __restrict__ vimg) {
  int y = blockIdx.x, b = blockIdx.y;
  int tid = threadIdx.x;
  u16* row = vimg + ((long)(b * 116 + y)) * 116 * 512;
  u16x8 z = {};
  if (y < 2 || y >= 114) {
    for (int i = tid; i < 116 * 512 / 8; i += 256) *(u16x8*)(row + i * 8) = z;
  } else {
    int col = tid >> 6;
    int x = (col < 2) ? col : 112 + col;
    *(u16x8*)(row + x * 512 + (tid & 63) * 8) = z;
  }
}

// ---------- LePE depthwise 5x5: rolling window, 2 x-positions/thread ----------
__global__ __launch_bounds__(256, 2)
void lepe_conv4(const u16* __restrict__ vimg, const float* __restrict__ wle,
                const float* __restrict__ lb, u16* __restrict__ lepe) {
  const int tid = threadIdx.x;
  const int c0 = (tid & 127) * 4;
  const int x0 = blockIdx.x * 4 + (tid >> 7) * 2;   // 0..110 (even)
  const int ys = blockIdx.y * 14;
  const int b  = blockIdx.z;
  f32x4 wv[25];
#pragma unroll
  for (int k = 0; k < 25; k++) wv[k] = *(const f32x4*)(wle + k * 512 + c0);
  const f32x4 bias = *(const f32x4*)(lb + c0);
  const u16* rbase = vimg + (((long)(b * 116 + ys)) * 116 + x0) * 512 + c0;
  u16x4 win[5][6];
#pragma unroll
  for (int j = 0; j < 4; j++) {
    const u16* rp = rbase + (long)j * (116 * 512);
#pragma unroll
    for (int kx = 0; kx < 6; kx++) win[j][kx] = *(const u16x4*)(rp + kx * 512);
  }
  const int gj0 = x0 / 7, wj0 = x0 - gj0 * 7;
  const int gj1 = (x0 + 1) / 7, wj1 = (x0 + 1) - gj1 * 7;
  u16* ob0 = lepe + (((long)(b * 256 + blockIdx.y * 32 + gj0)) * 49 + wj0) * 512 + c0;
  u16* ob1 = lepe + (((long)(b * 256 + blockIdx.y * 32 + gj1)) * 49 + wj1) * 512 + c0;
#pragma unroll
  for (int i = 0; i < 14; i++) {
    {
      const u16* rp = rbase + (long)(i + 4) * (116 * 512);
#pragma unroll
      for (int kx = 0; kx < 6; kx++) win[(i + 4) % 5][kx] = *(const u16x4*)(rp + kx * 512);
    }
    f32x4 a0 = bias, a1 = bias;
#pragma unroll
    for (int s = 0; s < 5; s++)
#pragma unroll
      for (int kx = 0; kx < 5; kx++) {
        u16x4 v0 = win[(i + s) % 5][kx];
        u16x4 v1 = win[(i + s) % 5][kx + 1];
        f32x4 w = wv[s * 5 + kx];
#pragma unroll
        for (int c = 0; c < 4; c++) {
          a0[c] += bf2f(v0[c]) * w[c];
          a1[c] += bf2f(v1[c]) * w[c];
        }
      }
    u16x4 o0, o1;
#pragma unroll
    for (int c = 0; c < 4; c++) { o0[c] = f2bf(a0[c]); o1[c] = f2bf(a1[c]); }
    long so = (long)((i / 7) * 784 + (i % 7) * 7) * 512;
    *(u16x4*)(ob0 + so) = o0;
    *(u16x4*)(ob1 + so) = o1;
  }
}

// ---------- per-window k^T v (MFMA) + k_sum + q·k_sum ----------
__global__ __launch_bounds__(256)
void kv_local_kernel(const u16* __restrict__ qk, const u16* __restrict__ vimg,
                     u16* __restrict__ KVl, float* __restrict__ qk_sum) {
  int n = blockIdx.x, h = blockIdx.y, b = blockIdx.z;
  int bh = b * HEADS + h;
  long tbase = ((long)(b * NB + n)) * WTOK;
  const int gi = n >> 4, gj = n & 15;
  __shared__ u16 kT[64 * 72];
  __shared__ u16 vT[64 * 72];
  __shared__ u16 qs[49 * 72];
  __shared__ float ksum[64];
  __shared__ float qkp[256];
  int tid = threadIdx.x;
  for (int i = tid; i < (64 * 72) / 2; i += 256) {
    ((u32*)kT)[i] = 0;
    ((u32*)vT)[i] = 0;
  }
  __syncthreads();
  {
    int w = tid >> 3, d0 = (tid & 7) * 8;
    u16x8 k8 = *(const u16x8*)(qk + (tbase + w) * 1024 + 512 + h * 64 + d0);
    int wi = w / 7, wj = w - wi * 7;
    long va = (((long)(b * 116 + gi * 7 + wi + 2)) * 116 + (gj * 7 + wj + 2)) * 512 + h * 64 + d0;
    u16x8 v8 = *(const u16x8*)(vimg + va);
#pragma unroll
    for (int i = 0; i < 8; i++) { kT[(d0 + i) * 72 + w] = k8[i]; vT[(d0 + i) * 72 + w] = v8[i]; }
    int w2 = w + 32;
    if (w2 < WTOK) {
      u16x8 k82 = *(const u16x8*)(qk + (tbase + w2) * 1024 + 512 + h * 64 + d0);
      int wi2 = w2 / 7, wj2 = w2 - wi2 * 7;
      long va2 = (((long)(b * 116 + gi * 7 + wi2 + 2)) * 116 + (gj * 7 + wj2 + 2)) * 512 + h * 64 + d0;
      u16x8 v82 = *(const u16x8*)(vimg + va2);
#pragma unroll
      for (int i = 0; i < 8; i++) { kT[(d0 + i) * 72 + w2] = k82[i]; vT[(d0 + i) * 72 + w2] = v82[i]; }
    }
    if (tid < 196) {
      int wq = tid >> 2, dq = (tid & 3) * 16;
      u16x8 q0 = *(const u16x8*)(qk + (tbase + wq) * 1024 + h * 64 + dq);
      u16x8 q1 = *(const u16x8*)(qk + (tbase + wq) * 1024 + h * 64 + dq + 8);
      *(u16x8*)&qs[wq * 72 + dq] = q0;
      *(u16x8*)&qs[wq * 72 + dq + 8] = q1;
    }
  }
  __syncthreads();
  if (tid < 64) {
    float s = 0.0f;
#pragma unroll
    for (int c = 0; c < 9; c++) {
      u16x8 r = *(const u16x8*)&kT[tid * 72 + c * 8];
#pragma unroll
      for (int i = 0; i < 8; i++) s += bf2f(r[i]);
    }
    ksum[tid] = s;
  }
  __syncthreads();
  if (tid < 196) {
    int w = tid >> 2, d0 = (tid & 3) * 16;
    float s = 0.0f;
#pragma unroll
    for (int i = 0; i < 16; i++) s += bf2f(qs[w * 72 + d0 + i]) * ksum[d0 + i];
    qkp[tid] = s;
  }
  __syncthreads();
  if (tid < WTOK) {
    float s = qkp[tid * 4] + qkp[tid * 4 + 1] + qkp[tid * 4 + 2] + qkp[tid * 4 + 3];
    qk_sum[((long)bh * NB + n) * WTOK + tid] = s;
  }
  int lane = tid & 63, wave = tid >> 6;
  int fr = lane & 15, fq = lane >> 4;
  f32x4 acc[4] = {};
#pragma unroll
  for (int ks = 0; ks < 2; ks++) {
    bf16x8 a = *(const bf16x8*)&kT[(wave * 16 + fr) * 72 + ks * 32 + fq * 8];
#pragma unroll
    for (int n4 = 0; n4 < 4; n4++) {
      bf16x8 bb = *(const bf16x8*)&vT[(n4 * 16 + fr) * 72 + ks * 32 + fq * 8];
      acc[n4] = MFMA_BF16(a, bb, acc[n4], 0, 0, 0);
    }
  }
  long obase = ((long)bh * NB + n) * 4096;
#pragma unroll
  for (int n4 = 0; n4 < 4; n4++)
#pragma unroll
    for (int jj = 0; jj < 4; jj++) {
      int d = wave * 16 + fq * 4 + jj;
      int e = n4 * 16 + fr;
      KVl[obase + d * 64 + e] = f2bf(acc[n4][jj]);
    }
}

// ---------- transpose KVl [bh][256][4096] -> KVT [bh][4096][256] ----------
__global__ __launch_bounds__(256)
void transpose_kv(const u16* __restrict__ in, u16* __restrict__ out) {
  int dt = blockIdx.x, jt = blockIdx.y, bh = blockIdx.z;
  __shared__ u16 t[64 * 72];
  int tid = threadIdx.x;
  {
    int jr = tid >> 2, c0 = (tid & 3) * 16;
    const u16* ip = in + ((long)bh * NB + jt * 64 + jr) * 4096 + dt * 64 + c0;
    *(u16x8*)&t[jr * 72 + c0] = *(const u16x8*)ip;
    *(u16x8*)&t[jr * 72 + c0 + 8] = *(const u16x8*)(ip + 8);
  }
  __syncthreads();
  {
    int der = tid >> 2, j0 = (tid & 3) * 16;
    u16x8 o0, o1;
#pragma unroll
    for (int i = 0; i < 8; i++) o0[i] = t[(j0 + i) * 72 + der];
#pragma unroll
    for (int i = 0; i < 8; i++) o1[i] = t[(j0 + 8 + i) * 72 + der];
    u16* op = out + ((long)bh * 4096 + dt * 64 + der) * 256 + jt * 64 + j0;
    *(u16x8*)op = o0;
    *(u16x8*)(op + 8) = o1;
  }
}

// ---------- normalizer: inv = 1/(Wt^T-mix of qk_sum + eps) ----------
__global__ __launch_bounds__(256)
void norm_kernel(const float* __restrict__ Wt, const float* __restrict__ qk_sum,
                 float* __restrict__ inv_norm) {
  int bh = blockIdx.x, tid = threadIdx.x;
  __shared__ float qk[NB * WTOK];
  for (int i = tid; i < NB * WTOK; i += 256) qk[i] = qk_sum[(long)bh * NB * WTOK + i];
  __syncthreads();
  float acc[WTOK];
#pragma unroll
  for (int w = 0; w < WTOK; w++) acc[w] = 0.0f;
  for (int j = 0; j < NB; j++) {
    float wv = Wt[j * NB + tid];
#pragma unroll
    for (int w = 0; w < WTOK; w++) acc[w] += wv * qk[j * WTOK + w];
  }
  long ob = ((long)bh * NB + tid) * WTOK;
#pragma unroll
  for (int w = 0; w < WTOK; w++) inv_norm[ob + w] = 1.0f / (acc[w] + 1e-6f);
}

// ---------- out = (q @ kvm) * inv_norm + lepe -> ebuf (bf16) ----------
__global__ __launch_bounds__(256)
void attn_out_kernel(const u16* __restrict__ qk, const u16* __restrict__ kvm,
                     const float* __restrict__ inv_norm, const u16* __restrict__ lepe,
                     u16* __restrict__ ebuf) {
  int n = blockIdx.x, h = blockIdx.y, b = blockIdx.z;
  int bh = b * HEADS + h;
  long tbase = ((long)(b * NB + n)) * WTOK;
  __shared__ u16 qs[64 * 72];
  __shared__ u16 kvT[64 * 72];
  __shared__ float inv[WTOK];
  int tid = threadIdx.x;
  if (tid < 196) {
    int w = tid >> 2, d0 = (tid & 3) * 16;
    u16x8 q0 = *(const u16x8*)(qk + (tbase + w) * 1024 + h * 64 + d0);
    u16x8 q1 = *(const u16x8*)(qk + (tbase + w) * 1024 + h * 64 + d0 + 8);
    *(u16x8*)&qs[w * 72 + d0] = q0;
    *(u16x8*)&qs[w * 72 + d0 + 8] = q1;
  }
  {
    int d = tid >> 2, e0 = (tid & 3) * 16;
    const u16* kp = kvm + ((long)bh * NB + n) * 4096 + d * 64 + e0;
    u16x8 k0 = *(const u16x8*)kp;
    u16x8 k1 = *(const u16x8*)(kp + 8);
#pragma unroll
    for (int i = 0; i < 8; i++) { kvT[(e0 + i) * 72 + d] = k0[i]; kvT[(e0 + 8 + i) * 72 + d] = k1[i]; }
  }
  if (tid < WTOK) inv[tid] = inv_norm[((long)bh * NB + n) * WTOK + tid];
  __syncthreads();
  int lane = tid & 63, wave = tid >> 6;
  int fr = lane & 15, fq = lane >> 4;
  f32x4 acc[4] = {};
#pragma unroll
  for (int ks = 0; ks < 2; ks++) {
    bf16x8 a = *(const bf16x8*)&qs[(wave * 16 + fr) * 72 + ks * 32 + fq * 8];
#pragma unroll
    for (int n4 = 0; n4 < 4; n4++) {
      bf16x8 bb = *(const bf16x8*)&kvT[(n4 * 16 + fr) * 72 + ks * 32 + fq * 8];
      acc[n4] = MFMA_BF16(a, bb, acc[n4], 0, 0, 0);
    }
  }
#pragma unroll
  for (int n4 = 0; n4 < 4; n4++)
#pragma unroll
    for (int jj = 0; jj < 4; jj++) {
      int w = wave * 16 + fq * 4 + jj;
      if (w < WTOK) {
        int e = n4 * 16 + fr;
        long off = (tbase + w) * CH + h * 64 + e;
        float v = acc[n4][jj] * inv[w] + bf2f(lepe[off]);
        ebuf[off] = f2bf(v);
      }
    }
}

// ---------- workspace layout ----------
static const size_t OFF_XN    = 0;                         // xn, then lepe (102,760,448)
static const size_t OFF_QKV   = 102760448;                 // qk [tok][1024] (205,520,896) + ebuf (102,760,448)
static const size_t OFF_EBUF  = OFF_QKV + 205520896;
static const size_t OFF_KVL   = OFF_QKV + 308281344;       // KVl, then kvm (134,217,728)
static const size_t OFF_KVT   = OFF_KVL + 134217728;       // vimg, then KVT (134,217,728)
static const size_t OFF_QKS   = OFF_KVT + 134217728;
static const size_t OFF_INV   = OFF_QKS + 3211264;
static const size_t OFF_WBF   = OFF_INV + 3211264;
static const size_t OFF_WTF   = OFF_WBF + 131072;
static const size_t OFF_WQKVB = OFF_WTF + 262144;
static const size_t OFF_WOUTB = OFF_WQKVB + 1572864;
static const size_t OFF_WLE   = OFF_WOUTB + 524288;

extern "C" void kernel_launch(void* const* d_in, const int* in_sizes, int n_in,
                              void* d_out, int out_size, void* d_ws, size_t ws_size,
                              hipStream_t stream) {
  const float* x      = (const float*)d_in[0];
  const float* ln_g   = (const float*)d_in[1];
  const float* ln_b   = (const float*)d_in[2];
  const float* w_qkv  = (const float*)d_in[3];
  const float* lepe_w = (const float*)d_in[4];
  const float* lepe_b = (const float*)d_in[5];
  const float* w_out  = (const float*)d_in[6];
  const float* b_out  = (const float*)d_in[7];
  float* out = (float*)d_out;
  char* ws = (char*)d_ws;

  u16*   xn     = (u16*)(ws + OFF_XN);
  u16*   lepe   = (u16*)(ws + OFF_XN);     // reuse after GEMM1
  u16*   qk     = (u16*)(ws + OFF_QKV);    // [tok][1024]
  u16*   ebuf   = (u16*)(ws + OFF_EBUF);
  u16*   KVl    = (u16*)(ws + OFF_KVL);
  u16*   kvm    = (u16*)(ws + OFF_KVL);    // reuse after transpose
  u16*   vimg   = (u16*)(ws + OFF_KVT);    // padded v image, dead after kv_local
  u16*   KVT    = (u16*)(ws + OFF_KVT);    // written after kv_local
  float* qks    = (float*)(ws + OFF_QKS);
  float* invn   = (float*)(ws + OFF_INV);
  u16*   Wbf    = (u16*)(ws + OFF_WBF);
  float* Wt     = (float*)(ws + OFF_WTF);
  u16*   wqkvb  = (u16*)(ws + OFF_WQKVB);
  u16*   woutb  = (u16*)(ws + OFF_WOUTB);
  float* wle    = (float*)(ws + OFF_WLE);

  cvt_f32_bf16<<<384, 256, 0, stream>>>(w_qkv, wqkvb, 98304);
  cvt_f32_bf16<<<128, 256, 0, stream>>>(w_out, woutb, 32768);
  prep_wle<<<50, 256, 0, stream>>>(lepe_w, wle);
  weight_kernel<<<256, 256, 0, stream>>>(Wbf, Wt);
  zero_border<<<dim3(116, 8), 256, 0, stream>>>(vimg);

  ln_kernel<<<25088, 256, 0, stream>>>(x, ln_g, ln_b, xn);

  // qkv GEMM (8-phase m201 template): q,k (relu+eps) -> qk; v -> vimg (fused fold)
  gemmT<1><<<2352, 512, 0, stream>>>(xn, wqkvb, (void*)qk, vimg, nullptr, 1024, 6);

  lepe_conv4<<<dim3(28, 8, 8), 256, 0, stream>>>(vimg, wle, lepe_b, lepe);

  kv_local_kernel<<<dim3(NB, HEADS, 8), 256, 0, stream>>>(qk, vimg, KVl, qks);

  transpose_kv<<<dim3(64, 4, 64), 256, 0, stream>>>(KVl, KVT);

  // kvm[bh] = W @ KV[bh]
  gemm_bt<0><<<dim3(32, 2, 64), 256, 0, stream>>>(Wbf, KVT, (void*)kvm, nullptr,
                                                  NB, 4096, NB,
                                                  0, (long)4096 * 256, (long)256 * 4096);

  norm_kernel<<<64, 256, 0, stream>>>(Wt, qks, invn);

  attn_out_kernel<<<dim3(NB, HEADS, 8), 256, 0, stream>>>(qk, kvm, invn, lepe, ebuf);

  // final projection: out = ebuf @ w_out^T + b_out (fp32 out, 8-phase)
  gemmT<2><<<784, 512, 0, stream>>>(ebuf, woutb, (void*)out, nullptr, b_out, 512, 2);
}

// Round 12
// 871.343 us; speedup vs baseline: 1.0479x; 1.0479x over previous
//
#include <hip/hip_runtime.h>
#include <cstdint>

typedef unsigned short u16;
typedef unsigned int   u32;
typedef u16   u16x8 __attribute__((ext_vector_type(8)));
typedef u16   u16x4 __attribute__((ext_vector_type(4)));
typedef float f32x4 __attribute__((ext_vector_type(4)));
typedef __bf16 bf16x8 __attribute__((ext_vector_type(8)));

#define NB    256      // windows (16x16 grid)
#define WTOK  49       // tokens per window (7x7)
#define CH    512
#define HEADS 8
#define DH    64
#define TOK   100352   // 8*256*49

#define MFMA_BF16 __builtin_amdgcn_mfma_f32_16x16x32_bf16

// ---------- helpers ----------
__device__ __forceinline__ u16 f2bf(float f) {
  u32 u = __float_as_uint(f);
  u = (u + 0x7FFFu + ((u >> 16) & 1u)) >> 16;
  return (u16)u;
}
__device__ __forceinline__ float bf2f(u16 u) { return __uint_as_float(((u32)u) << 16); }

__device__ __forceinline__ void load_lds16(const void* g, void* l) {
  __builtin_amdgcn_global_load_lds(
      reinterpret_cast<__attribute__((address_space(1))) void*>(reinterpret_cast<uintptr_t>(g)),
      reinterpret_cast<__attribute__((address_space(3))) void*>(reinterpret_cast<uintptr_t>(l)),
      16, 0, 0);
}

// ---------- small prep kernels ----------
__global__ void cvt_f32_bf16(const float* __restrict__ in, u16* __restrict__ out, int n8) {
  int i = blockIdx.x * 256 + threadIdx.x;
  if (i < n8) {
    f32x4 a = *(const f32x4*)(in + (long)i * 8);
    f32x4 b = *(const f32x4*)(in + (long)i * 8 + 4);
    u16x8 o;
    o[0]=f2bf(a[0]); o[1]=f2bf(a[1]); o[2]=f2bf(a[2]); o[3]=f2bf(a[3]);
    o[4]=f2bf(b[0]); o[5]=f2bf(b[1]); o[6]=f2bf(b[2]); o[7]=f2bf(b[3]);
    *(u16x8*)(out + (long)i * 8) = o;
  }
}

__global__ void prep_wle(const float* __restrict__ lepe_w, float* __restrict__ wle) {
  int i = blockIdx.x * 256 + threadIdx.x;   // 12800 = 512*25
  if (i < 12800) {
    int c = i / 25, kk = i % 25;
    wle[kk * 512 + c] = lepe_w[i];
  }
}

// block-weight matrix: mat[i,j] = cos(d(i,j)/dmax * pi/4), column-normalized over i
__global__ void weight_kernel(u16* __restrict__ Wbf, float* __restrict__ Wt) {
  int j = blockIdx.x, i = threadIdx.x;
  float iy = (float)(i >> 4) + 0.5f, ix = (float)(i & 15) + 0.5f;
  float jy = (float)(j >> 4) + 0.5f, jx = (float)(j & 15) + 0.5f;
  float dy = iy - jy, dx = ix - jx;
  float d = sqrtf(dy * dy + dx * dx);
  const float dmax = 21.213203435596427f;           // sqrt(450)
  float m = cosf(d * (0.78539816339744831f / dmax)); // pi/4 / dmax
  __shared__ float red[256];
  red[i] = m;
  __syncthreads();
  for (int s = 128; s > 0; s >>= 1) {
    if (i < s) red[i] += red[i + s];
    __syncthreads();
  }
  float w = m / red[0];
  Wbf[i * 256 + j] = f2bf(w);
  Wt[j * 256 + i] = w;
}

// ---------- LayerNorm (wave per token) ----------
__global__ __launch_bounds__(256) void ln_kernel(const float* __restrict__ x,
                                                 const float* __restrict__ g,
                                                 const float* __restrict__ bta,
                                                 u16* __restrict__ xn) {
  int wave = threadIdx.x >> 6, lane = threadIdx.x & 63;
  long t = (long)blockIdx.x * 4 + wave;
  const float* xp = x + t * CH + lane * 8;
  f32x4 a = *(const f32x4*)xp;
  f32x4 b = *(const f32x4*)(xp + 4);
  float s  = a[0]+a[1]+a[2]+a[3]+b[0]+b[1]+b[2]+b[3];
  float sq = a[0]*a[0]+a[1]*a[1]+a[2]*a[2]+a[3]*a[3]+b[0]*b[0]+b[1]*b[1]+b[2]*b[2]+b[3]*b[3];
  for (int m = 1; m < 64; m <<= 1) { s += __shfl_xor(s, m); sq += __shfl_xor(sq, m); }
  float mu = s * (1.0f / 512.0f);
  float var = sq * (1.0f / 512.0f) - mu * mu;
  float rstd = rsqrtf(var + 1e-5f);
  const float* gp = g + lane * 8;
  const float* bp = bta + lane * 8;
  f32x4 g0 = *(const f32x4*)gp, g1 = *(const f32x4*)(gp + 4);
  f32x4 b0 = *(const f32x4*)bp, b1 = *(const f32x4*)(bp + 4);
  u16x8 o;
  o[0] = f2bf((a[0]-mu)*rstd*g0[0] + b0[0]);
  o[1] = f2bf((a[1]-mu)*rstd*g0[1] + b0[1]);
  o[2] = f2bf((a[2]-mu)*rstd*g0[2] + b0[2]);
  o[3] = f2bf((a[3]-mu)*rstd*g0[3] + b0[3]);
  o[4] = f2bf((b[0]-mu)*rstd*g1[0] + b1[0]);
  o[5] = f2bf((b[1]-mu)*rstd*g1[1] + b1[1]);
  o[6] = f2bf((b[2]-mu)*rstd*g1[2] + b1[2]);
  o[7] = f2bf((b[3]-mu)*rstd*g1[3] + b1[3]);
  *(u16x8*)(xn + t * CH + lane * 8) = o;
}

// ======== 256x128 double-buffered GEMM, 2 blocks/CU ========
// C[M,N] = A[M,512] * B[N,512]^T.  8 waves (4M x 2N), per-wave 64x64.
// EPI=1: relu+eps on cols<1024 -> qk[tok][1024]; cols>=1024 -> vimg (fold_v fused)
// EPI=2: f32 out + bias
template <int KT>
__device__ __forceinline__ void kstepD(char* sm, const u16* sA, const u16* sB,
                                       int t, int lane_off, int wm, int wn,
                                       f32x4 (&acc)[4][4]) {
  if constexpr (KT + 1 < 16) {
    char* d = sm + ((KT + 1) & 1) * 24576 + t * 16;
    load_lds16(sA + (KT + 1) * 32, d);
    load_lds16(sA + 128 * 512 + (KT + 1) * 32, d + 8192);
    load_lds16(sB + (KT + 1) * 32, d + 16384);
  }
  const char* base = sm + (KT & 1) * 24576 + lane_off;
  bf16x8 fa[4], fb[4];
#pragma unroll
  for (int m = 0; m < 4; m++) fa[m] = *(const bf16x8*)(base + (wm * 4 + m) * 1024);
#pragma unroll
  for (int n = 0; n < 4; n++) fb[n] = *(const bf16x8*)(base + 16384 + (wn * 4 + n) * 1024);
  __builtin_amdgcn_s_setprio(1);
#pragma unroll
  for (int m = 0; m < 4; m++)
#pragma unroll
    for (int n = 0; n < 4; n++)
      acc[m][n] = MFMA_BF16(fa[m], fb[n], acc[m][n], 0, 0, 0);
  __builtin_amdgcn_s_setprio(0);
  if constexpr (KT + 1 < 16) __syncthreads();
}

template <int EPI>
__global__ __launch_bounds__(512, 4)
void gemmD(const u16* __restrict__ A, const u16* __restrict__ B,
           void* __restrict__ C, u16* __restrict__ vimg,
           const float* __restrict__ bias, int ldc, int nbn) {
  __shared__ __align__(16) char sm[49152];
  const int nwg = gridDim.x, bid = blockIdx.x;
  const int cpx = nwg >> 3;
  const int vid = (bid & 7) * cpx + (bid >> 3);   // XCD-contiguous chunks
  const int bn = vid % nbn, bm = vid / nbn;
  const int t = threadIdx.x, lane = t & 63, wave = t >> 6;
  const int wm = wave >> 1, wn = wave & 1;
  const int fr = lane & 15, fq = lane >> 4;
  const int lane_off = (fr >> 1) * 128 + ((((fr & 1) << 2) + fq) ^ (fr >> 1)) * 16;
  const int sl = (t & 7) ^ ((t >> 3) & 7);
  const u16* sA = A + ((long)bm * 256 + ((t >> 3) << 1) + (sl >> 2)) * 512 + (sl & 3) * 8;
  const u16* sB = B + ((long)bn * 128 + ((t >> 3) << 1) + (sl >> 2)) * 512 + (sl & 3) * 8;
  f32x4 acc[4][4] = {};
  {
    char* d = sm + t * 16;
    load_lds16(sA, d);
    load_lds16(sA + 128 * 512, d + 8192);
    load_lds16(sB, d + 16384);
  }
  __syncthreads();
  kstepD<0>(sm, sA, sB, t, lane_off, wm, wn, acc);
  kstepD<1>(sm, sA, sB, t, lane_off, wm, wn, acc);
  kstepD<2>(sm, sA, sB, t, lane_off, wm, wn, acc);
  kstepD<3>(sm, sA, sB, t, lane_off, wm, wn, acc);
  kstepD<4>(sm, sA, sB, t, lane_off, wm, wn, acc);
  kstepD<5>(sm, sA, sB, t, lane_off, wm, wn, acc);
  kstepD<6>(sm, sA, sB, t, lane_off, wm, wn, acc);
  kstepD<7>(sm, sA, sB, t, lane_off, wm, wn, acc);
  kstepD<8>(sm, sA, sB, t, lane_off, wm, wn, acc);
  kstepD<9>(sm, sA, sB, t, lane_off, wm, wn, acc);
  kstepD<10>(sm, sA, sB, t, lane_off, wm, wn, acc);
  kstepD<11>(sm, sA, sB, t, lane_off, wm, wn, acc);
  kstepD<12>(sm, sA, sB, t, lane_off, wm, wn, acc);
  kstepD<13>(sm, sA, sB, t, lane_off, wm, wn, acc);
  kstepD<14>(sm, sA, sB, t, lane_off, wm, wn, acc);
  kstepD<15>(sm, sA, sB, t, lane_off, wm, wn, acc);
  // ---- epilogue: per-wave LDS repack -> vectorized stores ----
  __syncthreads();
  {
    float* ep = (float*)sm + wave * 1088;      // [16 rows][68 f32] per wave
    const long r0 = (long)bm * 256 + wm * 64;
    const int c0 = bn * 128 + wn * 64;
    const int rrow = lane >> 2;
    const int cb = (lane & 3) * 16;
    const int cc = c0 + cb;
#pragma unroll
    for (int m = 0; m < 4; m++) {
#pragma unroll
      for (int n = 0; n < 4; n++) {
        int c = c0 + n * 16 + fr;
        float badd = (EPI == 2) ? bias[c] : 0.0f;
#pragma unroll
        for (int jj = 0; jj < 4; jj++) {
          float v = acc[m][n][jj];
          if (EPI == 1) { if (c < 1024) v = fmaxf(v, 0.0f) + 1e-6f; }
          if (EPI == 2) v += badd;
          ep[(fq * 4 + jj) * 68 + n * 16 + fr] = v;
        }
      }
      f32x4 rr[4];
#pragma unroll
      for (int i = 0; i < 4; i++)
        rr[i] = *(const f32x4*)&ep[rrow * 68 + cb + i * 4];
      long gr = r0 + m * 16 + rrow;
      if (EPI == 2) {
        float* gp = (float*)C + gr * ldc + cc;
#pragma unroll
        for (int i = 0; i < 4; i++) *(f32x4*)(gp + i * 4) = rr[i];
      } else {
        u16x8 o0, o1;
#pragma unroll
        for (int i = 0; i < 4; i++) {
          o0[i] = f2bf(rr[0][i]); o0[4 + i] = f2bf(rr[1][i]);
          o1[i] = f2bf(rr[2][i]); o1[4 + i] = f2bf(rr[3][i]);
        }
        u16* gp;
        if (cc < 1024) {
          gp = (u16*)C + gr * ldc + cc;
        } else {
          // fused fold_v: token -> padded image position
          int tok = (int)gr;
          int b2 = tok / 12544;
          int rem = tok - b2 * 12544;
          int nn = rem / 49;
          int w = rem - nn * 49;
          int wi = w / 7, wj = w - wi * 7;
          int y = (nn >> 4) * 7 + wi + 2;
          int xx = (nn & 15) * 7 + wj + 2;
          gp = vimg + (((long)(b2 * 116 + y)) * 116 + xx) * 512 + (cc - 1024);
        }
        *(u16x8*)gp = o0;
        *(u16x8*)(gp + 8) = o1;
      }
    }
  }
}

// ---------- fused mix GEMM: kvm[bh][i][de] = sum_j W[i][j] * KVl[bh][j][de] ----------
// Replaces transpose_kv + gemm_bt: B-tile staged LINEARLY [32 j][128 de] via
// global_load_lds; transpose happens in fragment reads (8 scalar u16 along j).
__global__ __launch_bounds__(256)
void gemm_mix(const u16* __restrict__ W, const u16* __restrict__ KVl,
              u16* __restrict__ kvm) {
  __shared__ u16 As[128 * 32];     // [i][j]
  __shared__ u16 Bs[32 * 128];     // [j][de] linear
  const int tid = threadIdx.x;
  const int lane = tid & 63, wave = tid >> 6;
  const int fr = lane & 15, fq = lane >> 4;
  const int wr = (wave >> 1) * 64, wc = (wave & 1) * 64;
  const int bn = blockIdx.x;       // de-tile (0..31)
  const int bm = blockIdx.y;       // i-tile (0..1)
  const int bh = blockIdx.z;
  const u16* Ab = W + (long)bm * 128 * 256;
  const u16* Bb = KVl + ((long)bh * 256) * 4096 + bn * 128;
  const int srow = tid >> 2, scol = (tid & 3) * 8;
  f32x4 acc[4][4] = {};
  for (int k0 = 0; k0 < 256; k0 += 32) {
    __syncthreads();   // prior step's LDS reads complete
    load_lds16(Ab + (long)srow * 256 + k0 + scol, As + tid * 8);
    load_lds16(Ab + (long)(srow + 64) * 256 + k0 + scol, As + 2048 + tid * 8);
    // B: chunk c covers (j = c>>4, seg = c&15)
    load_lds16(Bb + (long)(k0 + (tid >> 4)) * 4096 + (tid & 15) * 8, Bs + tid * 8);
    load_lds16(Bb + (long)(k0 + 16 + (tid >> 4)) * 4096 + (tid & 15) * 8, Bs + 2048 + tid * 8);
    __syncthreads();   // staging landed (vmcnt drained)
    bf16x8 af[4], bf[4];
#pragma unroll
    for (int m = 0; m < 4; m++) af[m] = *(const bf16x8*)&As[(wr + m * 16 + fr) * 32 + fq * 8];
#pragma unroll
    for (int n = 0; n < 4; n++) {
      union { u16 h[8]; bf16x8 v; } u;
#pragma unroll
      for (int kk = 0; kk < 8; kk++)
        u.h[kk] = Bs[(fq * 8 + kk) * 128 + wc + n * 16 + fr];
      bf[n] = u.v;
    }
#pragma unroll
    for (int m = 0; m < 4; m++)
#pragma unroll
      for (int n = 0; n < 4; n++)
        acc[m][n] = MFMA_BF16(af[m], bf[n], acc[m][n], 0, 0, 0);
  }
  const long obase = (long)bh * 256 * 4096;
#pragma unroll
  for (int m = 0; m < 4; m++) {
    int r0 = bm * 128 + wr + m * 16 + fq * 4;
#pragma unroll
    for (int n = 0; n < 4; n++) {
      int c = bn * 128 + wc + n * 16 + fr;
#pragma unroll
      for (int jj = 0; jj < 4; jj++)
        kvm[obase + (long)(r0 + jj) * 4096 + c] = f2bf(acc[m][n][jj]);
    }
  }
}

// zero the 2-wide border of vimg
__global__ __launch_bounds__(256)
void zero_border(u16* __restrict__ vimg) {
  int y = blockIdx.x, b = blockIdx.y;
  int tid = threadIdx.x;
  u16* row = vimg + ((long)(b * 116 + y)) * 116 * 512;
  u16x8 z = {};
  if (y < 2 || y >= 114) {
    for (int i = tid; i < 116 * 512 / 8; i += 256) *(u16x8*)(row + i * 8) = z;
  } else {
    int col = tid >> 6;
    int x = (col < 2) ? col : 112 + col;
    *(u16x8*)(row + x * 512 + (tid & 63) * 8) = z;
  }
}

// ---------- LePE depthwise 5x5: rolling window, 2 x-positions/thread ----------
__global__ __launch_bounds__(256, 2)
void lepe_conv4(const u16* __restrict__ vimg, const float* __restrict__ wle,
                const float* __restrict__ lb, u16* __restrict__ lepe) {
  const int tid = threadIdx.x;
  const int c0 = (tid & 127) * 4;
  const int x0 = blockIdx.x * 4 + (tid >> 7) * 2;   // 0..110 (even)
  const int ys = blockIdx.y * 14;
  const int b  = blockIdx.z;
  f32x4 wv[25];
#pragma unroll
  for (int k = 0; k < 25; k++) wv[k] = *(const f32x4*)(wle + k * 512 + c0);
  const f32x4 bias = *(const f32x4*)(lb + c0);
  const u16* rbase = vimg + (((long)(b * 116 + ys)) * 116 + x0) * 512 + c0;
  u16x4 win[5][6];
#pragma unroll
  for (int j = 0; j < 4; j++) {
    const u16* rp = rbase + (long)j * (116 * 512);
#pragma unroll
    for (int kx = 0; kx < 6; kx++) win[j][kx] = *(const u16x4*)(rp + kx * 512);
  }
  const int gj0 = x0 / 7, wj0 = x0 - gj0 * 7;
  const int gj1 = (x0 + 1) / 7, wj1 = (x0 + 1) - gj1 * 7;
  u16* ob0 = lepe + (((long)(b * 256 + blockIdx.y * 32 + gj0)) * 49 + wj0) * 512 + c0;
  u16* ob1 = lepe + (((long)(b * 256 + blockIdx.y * 32 + gj1)) * 49 + wj1) * 512 + c0;
#pragma unroll
  for (int i = 0; i < 14; i++) {
    {
      const u16* rp = rbase + (long)(i + 4) * (116 * 512);
#pragma unroll
      for (int kx = 0; kx < 6; kx++) win[(i + 4) % 5][kx] = *(const u16x4*)(rp + kx * 512);
    }
    f32x4 a0 = bias, a1 = bias;
#pragma unroll
    for (int s = 0; s < 5; s++)
#pragma unroll
      for (int kx = 0; kx < 5; kx++) {
        u16x4 v0 = win[(i + s) % 5][kx];
        u16x4 v1 = win[(i + s) % 5][kx + 1];
        f32x4 w = wv[s * 5 + kx];
#pragma unroll
        for (int c = 0; c < 4; c++) {
          a0[c] += bf2f(v0[c]) * w[c];
          a1[c] += bf2f(v1[c]) * w[c];
        }
      }
    u16x4 o0, o1;
#pragma unroll
    for (int c = 0; c < 4; c++) { o0[c] = f2bf(a0[c]); o1[c] = f2bf(a1[c]); }
    long so = (long)((i / 7) * 784 + (i % 7) * 7) * 512;
    *(u16x4*)(ob0 + so) = o0;
    *(u16x4*)(ob1 + so) = o1;
  }
}

// ---------- per-window k^T v (MFMA) + k_sum + q·k_sum ----------
__global__ __launch_bounds__(256)
void kv_local_kernel(const u16* __restrict__ qk, const u16* __restrict__ vimg,
                     u16* __restrict__ KVl, float* __restrict__ qk_sum) {
  int n = blockIdx.x, h = blockIdx.y, b = blockIdx.z;
  int bh = b * HEADS + h;
  long tbase = ((long)(b * NB + n)) * WTOK;
  const int gi = n >> 4, gj = n & 15;
  __shared__ u16 kT[64 * 72];
  __shared__ u16 vT[64 * 72];
  __shared__ u16 qs[49 * 72];
  __shared__ float ksum[64];
  __shared__ float qkp[256];
  int tid = threadIdx.x;
  for (int i = tid; i < (64 * 72) / 2; i += 256) {
    ((u32*)kT)[i] = 0;
    ((u32*)vT)[i] = 0;
  }
  __syncthreads();
  {
    int w = tid >> 3, d0 = (tid & 7) * 8;
    u16x8 k8 = *(const u16x8*)(qk + (tbase + w) * 1024 + 512 + h * 64 + d0);
    int wi = w / 7, wj = w - wi * 7;
    long va = (((long)(b * 116 + gi * 7 + wi + 2)) * 116 + (gj * 7 + wj + 2)) * 512 + h * 64 + d0;
    u16x8 v8 = *(const u16x8*)(vimg + va);
#pragma unroll
    for (int i = 0; i < 8; i++) { kT[(d0 + i) * 72 + w] = k8[i]; vT[(d0 + i) * 72 + w] = v8[i]; }
    int w2 = w + 32;
    if (w2 < WTOK) {
      u16x8 k82 = *(const u16x8*)(qk + (tbase + w2) * 1024 + 512 + h * 64 + d0);
      int wi2 = w2 / 7, wj2 = w2 - wi2 * 7;
      long va2 = (((long)(b * 116 + gi * 7 + wi2 + 2)) * 116 + (gj * 7 + wj2 + 2)) * 512 + h * 64 + d0;
      u16x8 v82 = *(const u16x8*)(vimg + va2);
#pragma unroll
      for (int i = 0; i < 8; i++) { kT[(d0 + i) * 72 + w2] = k82[i]; vT[(d0 + i) * 72 + w2] = v82[i]; }
    }
    if (tid < 196) {
      int wq = tid >> 2, dq = (tid & 3) * 16;
      u16x8 q0 = *(const u16x8*)(qk + (tbase + wq) * 1024 + h * 64 + dq);
      u16x8 q1 = *(const u16x8*)(qk + (tbase + wq) * 1024 + h * 64 + dq + 8);
      *(u16x8*)&qs[wq * 72 + dq] = q0;
      *(u16x8*)&qs[wq * 72 + dq + 8] = q1;
    }
  }
  __syncthreads();
  if (tid < 64) {
    float s = 0.0f;
#pragma unroll
    for (int c = 0; c < 9; c++) {
      u16x8 r = *(const u16x8*)&kT[tid * 72 + c * 8];
#pragma unroll
      for (int i = 0; i < 8; i++) s += bf2f(r[i]);
    }
    ksum[tid] = s;
  }
  __syncthreads();
  if (tid < 196) {
    int w = tid >> 2, d0 = (tid & 3) * 16;
    float s = 0.0f;
#pragma unroll
    for (int i = 0; i < 16; i++) s += bf2f(qs[w * 72 + d0 + i]) * ksum[d0 + i];
    qkp[tid] = s;
  }
  __syncthreads();
  if (tid < WTOK) {
    float s = qkp[tid * 4] + qkp[tid * 4 + 1] + qkp[tid * 4 + 2] + qkp[tid * 4 + 3];
    qk_sum[((long)bh * NB + n) * WTOK + tid] = s;
  }
  int lane = tid & 63, wave = tid >> 6;
  int fr = lane & 15, fq = lane >> 4;
  f32x4 acc[4] = {};
#pragma unroll
  for (int ks = 0; ks < 2; ks++) {
    bf16x8 a = *(const bf16x8*)&kT[(wave * 16 + fr) * 72 + ks * 32 + fq * 8];
#pragma unroll
    for (int n4 = 0; n4 < 4; n4++) {
      bf16x8 bb = *(const bf16x8*)&vT[(n4 * 16 + fr) * 72 + ks * 32 + fq * 8];
      acc[n4] = MFMA_BF16(a, bb, acc[n4], 0, 0, 0);
    }
  }
  long obase = ((long)bh * NB + n) * 4096;
#pragma unroll
  for (int n4 = 0; n4 < 4; n4++)
#pragma unroll
    for (int jj = 0; jj < 4; jj++) {
      int d = wave * 16 + fq * 4 + jj;
      int e = n4 * 16 + fr;
      KVl[obase + d * 64 + e] = f2bf(acc[n4][jj]);
    }
}

// ---------- normalizer: inv = 1/(Wt^T-mix of qk_sum + eps) ----------
__global__ __launch_bounds__(256)
void norm_kernel(const float* __restrict__ Wt, const float* __restrict__ qk_sum,
                 float* __restrict__ inv_norm) {
  int bh = blockIdx.x, tid = threadIdx.x;
  __shared__ float qk[NB * WTOK];
  for (int i = tid; i < NB * WTOK; i += 256) qk[i] = qk_sum[(long)bh * NB * WTOK + i];
  __syncthreads();
  float acc[WTOK];
#pragma unroll
  for (int w = 0; w < WTOK; w++) acc[w] = 0.0f;
  for (int j = 0; j < NB; j++) {
    float wv = Wt[j * NB + tid];
#pragma unroll
    for (int w = 0; w < WTOK; w++) acc[w] += wv * qk[j * WTOK + w];
  }
  long ob = ((long)bh * NB + tid) * WTOK;
#pragma unroll
  for (int w = 0; w < WTOK; w++) inv_norm[ob + w] = 1.0f / (acc[w] + 1e-6f);
}

// ---------- out = (q @ kvm) * inv_norm + lepe -> ebuf (bf16) ----------
__global__ __launch_bounds__(256)
void attn_out_kernel(const u16* __restrict__ qk, const u16* __restrict__ kvm,
                     const float* __restrict__ inv_norm, const u16* __restrict__ lepe,
                     u16* __restrict__ ebuf) {
  int n = blockIdx.x, h = blockIdx.y, b = blockIdx.z;
  int bh = b * HEADS + h;
  long tbase = ((long)(b * NB + n)) * WTOK;
  __shared__ u16 qs[64 * 72];
  __shared__ u16 kvT[64 * 72];
  __shared__ float inv[WTOK];
  int tid = threadIdx.x;
  if (tid < 196) {
    int w = tid >> 2, d0 = (tid & 3) * 16;
    u16x8 q0 = *(const u16x8*)(qk + (tbase + w) * 1024 + h * 64 + d0);
    u16x8 q1 = *(const u16x8*)(qk + (tbase + w) * 1024 + h * 64 + d0 + 8);
    *(u16x8*)&qs[w * 72 + d0] = q0;
    *(u16x8*)&qs[w * 72 + d0 + 8] = q1;
  }
  {
    int d = tid >> 2, e0 = (tid & 3) * 16;
    const u16* kp = kvm + ((long)bh * NB + n) * 4096 + d * 64 + e0;
    u16x8 k0 = *(const u16x8*)kp;
    u16x8 k1 = *(const u16x8*)(kp + 8);
#pragma unroll
    for (int i = 0; i < 8; i++) { kvT[(e0 + i) * 72 + d] = k0[i]; kvT[(e0 + 8 + i) * 72 + d] = k1[i]; }
  }
  if (tid < WTOK) inv[tid] = inv_norm[((long)bh * NB + n) * WTOK + tid];
  __syncthreads();
  int lane = tid & 63, wave = tid >> 6;
  int fr = lane & 15, fq = lane >> 4;
  f32x4 acc[4] = {};
#pragma unroll
  for (int ks = 0; ks < 2; ks++) {
    bf16x8 a = *(const bf16x8*)&qs[(wave * 16 + fr) * 72 + ks * 32 + fq * 8];
#pragma unroll
    for (int n4 = 0; n4 < 4; n4++) {
      bf16x8 bb = *(const bf16x8*)&kvT[(n4 * 16 + fr) * 72 + ks * 32 + fq * 8];
      acc[n4] = MFMA_BF16(a, bb, acc[n4], 0, 0, 0);
    }
  }
#pragma unroll
  for (int n4 = 0; n4 < 4; n4++)
#pragma unroll
    for (int jj = 0; jj < 4; jj++) {
      int w = wave * 16 + fq * 4 + jj;
      if (w < WTOK) {
        int e = n4 * 16 + fr;
        long off = (tbase + w) * CH + h * 64 + e;
        float v = acc[n4][jj] * inv[w] + bf2f(lepe[off]);
        ebuf[off] = f2bf(v);
      }
    }
}

// ---------- workspace layout ----------
static const size_t OFF_XN    = 0;                         // xn, then lepe (102,760,448)
static const size_t OFF_QKV   = 102760448;                 // qk [tok][1024] (205,520,896) + ebuf (102,760,448)
static const size_t OFF_EBUF  = OFF_QKV + 205520896;
static const size_t OFF_KVL   = OFF_QKV + 308281344;       // KVl (134,217,728)
static const size_t OFF_KVT   = OFF_KVL + 134217728;       // vimg, then kvm (134,217,728)
static const size_t OFF_QKS   = OFF_KVT + 134217728;
static const size_t OFF_INV   = OFF_QKS + 3211264;
static const size_t OFF_WBF   = OFF_INV + 3211264;
static const size_t OFF_WTF   = OFF_WBF + 131072;
static const size_t OFF_WQKVB = OFF_WTF + 262144;
static const size_t OFF_WOUTB = OFF_WQKVB + 1572864;
static const size_t OFF_WLE   = OFF_WOUTB + 524288;

extern "C" void kernel_launch(void* const* d_in, const int* in_sizes, int n_in,
                              void* d_out, int out_size, void* d_ws, size_t ws_size,
                              hipStream_t stream) {
  const float* x      = (const float*)d_in[0];
  const float* ln_g   = (const float*)d_in[1];
  const float* ln_b   = (const float*)d_in[2];
  const float* w_qkv  = (const float*)d_in[3];
  const float* lepe_w = (const float*)d_in[4];
  const float* lepe_b = (const float*)d_in[5];
  const float* w_out  = (const float*)d_in[6];
  const float* b_out  = (const float*)d_in[7];
  float* out = (float*)d_out;
  char* ws = (char*)d_ws;

  u16*   xn     = (u16*)(ws + OFF_XN);
  u16*   lepe   = (u16*)(ws + OFF_XN);     // reuse after GEMM1
  u16*   qk     = (u16*)(ws + OFF_QKV);    // [tok][1024]
  u16*   ebuf   = (u16*)(ws + OFF_EBUF);
  u16*   KVl    = (u16*)(ws + OFF_KVL);
  u16*   vimg   = (u16*)(ws + OFF_KVT);    // padded v image, dead after kv_local
  u16*   kvm    = (u16*)(ws + OFF_KVT);    // written by gemm_mix after kv_local
  float* qks    = (float*)(ws + OFF_QKS);
  float* invn   = (float*)(ws + OFF_INV);
  u16*   Wbf    = (u16*)(ws + OFF_WBF);
  float* Wt     = (float*)(ws + OFF_WTF);
  u16*   wqkvb  = (u16*)(ws + OFF_WQKVB);
  u16*   woutb  = (u16*)(ws + OFF_WOUTB);
  float* wle    = (float*)(ws + OFF_WLE);

  cvt_f32_bf16<<<384, 256, 0, stream>>>(w_qkv, wqkvb, 98304);
  cvt_f32_bf16<<<128, 256, 0, stream>>>(w_out, woutb, 32768);
  prep_wle<<<50, 256, 0, stream>>>(lepe_w, wle);
  weight_kernel<<<256, 256, 0, stream>>>(Wbf, Wt);
  zero_border<<<dim3(116, 8), 256, 0, stream>>>(vimg);

  ln_kernel<<<25088, 256, 0, stream>>>(x, ln_g, ln_b, xn);

  // qkv GEMM: q,k (relu+eps) -> qk[tok][1024]; v -> vimg (fold_v fused)
  gemmD<1><<<4704, 512, 0, stream>>>(xn, wqkvb, (void*)qk, vimg, nullptr, 1024, 12);

  lepe_conv4<<<dim3(28, 8, 8), 256, 0, stream>>>(vimg, wle, lepe_b, lepe);

  kv_local_kernel<<<dim3(NB, HEADS, 8), 256, 0, stream>>>(qk, vimg, KVl, qks);

  // fused mix (reads KVl directly; transpose in LDS fragment reads)
  gemm_mix<<<dim3(32, 2, 64), 256, 0, stream>>>(Wbf, KVl, kvm);

  norm_kernel<<<64, 256, 0, stream>>>(Wt, qks, invn);

  attn_out_kernel<<<dim3(NB, HEADS, 8), 256, 0, stream>>>(qk, kvm, invn, lepe, ebuf);

  // final projection: out = ebuf @ w_out^T + b_out (fp32 out)
  gemmD<2><<<1568, 512, 0, stream>>>(ebuf, woutb, (void*)out, nullptr, b_out, 512, 4);
}